// Round 9
// baseline (934.428 us; speedup 1.0000x reference)
//
#include <hip/hip_runtime.h>

#define B_   8
#define C_   96
#define H_   160
#define W_   320
#define ND   9
#define NDD  81
#define TH   16
#define TW   16
#define KC   3                  // channels per chunk; wave w stages channel cb+w
#define NCH  32
#define F2ROWS 18               // rows r0 .. r0+17 (out row + dh-in-group spans 0..17)
#define F2STRIDE 24             // dw per row (24 halo cols, no pad: phase-spread is free)
#define F2PLANE (F2ROWS*F2STRIDE)   // 432 dw per channel
#define BUFW (KC*F2PLANE)           // 1296 dw = 5184 B
#define LDSWORDS (2*BUFW)           // 10368 B -> LDS never the residency limit

#define AS1 __attribute__((address_space(1)))
#define AS3 __attribute__((address_space(3)))

__device__ __forceinline__ void gld16(const float* gp, float* lp) {
    // HBM/L2 -> LDS direct; LDS dest = wave-uniform base + lane*16
    __builtin_amdgcn_global_load_lds((const AS1 float*)gp,
                                     (AS3 float*)(unsigned long long)lp, 16, 0, 0);
}

__global__ __launch_bounds__(192, 6)    // VGPR cap 85 -> 6 waves/SIMD, 8 blocks/CU
void corr_kernel(const float* __restrict__ f1g,
                 const float* __restrict__ f2g,
                 float* __restrict__ out)
{
    __shared__ float lds[LDSWORDS];

    const int tid  = threadIdx.x;
    const int wave = tid >> 6;          // dh-within-group AND staging channel idx
    const int lane = tid & 63;
    const int row  = lane >> 2;         // 0..15
    const int m    = lane & 3;
    const int colb = m << 2;            // 0,4,8,12

    // XCD swizzle: 4800 = 8 XCDs x 600 (bijective). XCD owns batch b; the 3
    // dh-groups of a tile are dispatch-adjacent (halo/L2 reuse).
    const int bid  = blockIdx.x;
    const int ebid = (bid & 7) * 600 + (bid >> 3);
    const int b    = ebid / 600;
    const int t6   = ebid - b * 600;
    const int g    = t6 % 3;            // dh = 3g + wave
    const int tile = t6 / 3;
    const int by   = tile / 20, bx = tile - by * 20;
    const int x0 = bx * TW, y0 = by * TH;
    const int HWi  = H_ * W_;
    const int r0   = y0 + 3 * g - 4;    // first f2 halo row (global)

    const float* f1b = f1g + (size_t)b * C_ * HWi;
    const float* f2b = f2g + (size_t)b * C_ * HWi;

    // f1: direct global->reg, thread's own 4 px (L1-shared across the 3 waves)
    const float* f1p = f1b + (y0 + row) * W_ + x0 + colb;

    // f2 staging lane maps (2 gld16 parts per channel-plane of 432 dw):
    // slot s -> dw 4s, r = s/6, c = 4*(s%6); part0 s=lane, part1 s=64+lane (s<108).
    // Halo x-offset (4) == segment width (16B) -> a segment is either fully
    // in-bounds or fully out: predicate gx in [0, W-4] is exact.
    int so0, so1; bool p0, p1;
    {
        int s, r, c, gy, gx;
        s = lane;      r = s / 6; c = (s - 6 * r) << 2;
        gy = r0 + r;   gx = x0 - 4 + c;
        p0 = (gy >= 0) & (gy < H_) & (gx >= 0) & (gx <= W_ - 4);
        so0 = gy * W_ + gx;
        s = 64 + lane; r = s / 6; c = (s - 6 * r) << 2;
        gy = r0 + r;   gx = x0 - 4 + c;
        p1 = (s < 108) & (gy >= 0) & (gy < H_) & (gx >= 0) & (gx <= W_ - 4);
        so1 = gy * W_ + gx;
    }

    // compute-side read base: f2 lds row = out_row + wave
    const int o0 = (row + wave) * F2STRIDE + colb;

    // stage chunk cb..cb+2: wave w stages channel cb+w (2 predicated gld16)
    auto stage = [&](int cb, int bufb) {
        const int co = (cb + wave) * HWi;
        float* l = &lds[bufb + wave * F2PLANE];
        if (p0) gld16(f2b + co + so0, l);
        if (p1) gld16(f2b + co + so1, l + 256);
    };

    float4 acc0, acc1, acc2, acc3, acc4, acc5, acc6, acc7, acc8;
    acc0 = acc1 = acc2 = acc3 = acc4 = acc5 = acc6 = acc7 = acc8 = make_float4(0.f, 0.f, 0.f, 0.f);
    float4 P0, P1, P2;

#define F1LOAD(cb) {                                         \
        P0 = *(const float4*)(f1p + (cb) * HWi);             \
        P1 = *(const float4*)(f1p + ((cb) + 1) * HWi);       \
        P2 = *(const float4*)(f1p + ((cb) + 2) * HWi); }

#define STEPD(A, P, e0, e1, e2, e3)                          \
        A.x = fmaf(P.x, e0, A.x);                            \
        A.y = fmaf(P.y, e1, A.y);                            \
        A.z = fmaf(P.z, e2, A.z);                            \
        A.w = fmaf(P.w, e3, A.w);

#define COMPC(c, RB, P) {                                                         \
        const float4 q0 = *(const float4*)&lds[(RB) + c * F2PLANE + o0];          \
        const float4 q1 = *(const float4*)&lds[(RB) + c * F2PLANE + o0 + 4];      \
        const float4 q2 = *(const float4*)&lds[(RB) + c * F2PLANE + o0 + 8];      \
        STEPD(acc0, P, q0.x, q0.y, q0.z, q0.w)                                    \
        STEPD(acc1, P, q0.y, q0.z, q0.w, q1.x)                                    \
        STEPD(acc2, P, q0.z, q0.w, q1.x, q1.y)                                    \
        STEPD(acc3, P, q0.w, q1.x, q1.y, q1.z)                                    \
        STEPD(acc4, P, q1.x, q1.y, q1.z, q1.w)                                    \
        STEPD(acc5, P, q1.y, q1.z, q1.w, q2.x)                                    \
        STEPD(acc6, P, q1.z, q1.w, q2.x, q2.y)                                    \
        STEPD(acc7, P, q1.w, q2.x, q2.y, q2.z)                                    \
        STEPD(acc8, P, q2.x, q2.y, q2.z, q2.w)                                    \
    }

    // one-time zero (OOB slots are never DMA'd; payload rewritten every chunk)
    for (int t = tid; t < LDSWORDS; t += 192) lds[t] = 0.f;
    __syncthreads();
    stage(0, 0);                          // chunk 0 -> buf 0

#pragma unroll 1
    for (int kk = 0; kk < NCH / 2; ++kk) {
        const int c0 = 6 * kk;            // chunk 2kk channels c0..c0+2
        __syncthreads();                  // chunk-2kk DMA drained (vmcnt in barrier)
        F1LOAD(c0)                        // f1 regs BEFORE stage: no DMA drain on use
        stage(c0 + 3, BUFW);              // prefetch chunk 2kk+1 -> buf 1
        COMPC(0, 0, P0) COMPC(1, 0, P1) COMPC(2, 0, P2)
        __syncthreads();
        F1LOAD(c0 + 3)
        if (kk < NCH / 2 - 1) stage(c0 + 6, 0);
        COMPC(0, BUFW, P0) COMPC(1, BUFW, P1) COMPC(2, BUFW, P2)
    }

    // ---- epilogue: dh = 3g + wave; out[b, dh*9+d, y0+row, x0+colb..+3] ----
    const int dh = 3 * g + wave;
    const int gy = y0 + row;
    const int gx = x0 + colb;
#define STORED(d) {                                                                 \
        float* op_ = out + (size_t)((b * NDD + dh * ND + d) * H_ + gy) * W_ + gx;   \
        *(float4*)op_ = acc##d; }
    STORED(0) STORED(1) STORED(2) STORED(3) STORED(4)
    STORED(5) STORED(6) STORED(7) STORED(8)
}

extern "C" void kernel_launch(void* const* d_in, const int* in_sizes, int n_in,
                              void* d_out, int out_size, void* d_ws, size_t ws_size,
                              hipStream_t stream)
{
    const float* f1 = (const float*)d_in[0];
    const float* f2 = (const float*)d_in[1];
    float* out = (float*)d_out;
    corr_kernel<<<dim3(4800), 192, 0, stream>>>(f1, f2, out);
}

// Round 10
// 214.749 us; speedup vs baseline: 4.3513x; 4.3513x over previous
//
#include <hip/hip_runtime.h>

#define B_   8
#define C_   96
#define H_   160
#define W_   320
#define ND   9
#define NDD  81
#define TH   16
#define TW   16
#define KC   3                  // channels per chunk; wave w stages channel cb+w
#define NCH  32
#define F2ROWS 18               // rows r0 .. r0+17
#define F2STRIDE 24             // dw per row (no pad; b128 start-phases spread evenly)
#define F2PLANE (F2ROWS*F2STRIDE)   // 432 dw per channel
#define BUFW (KC*F2PLANE)           // 1296 dw = 5184 B
// LDS deliberately padded to 21504 B: 7 blocks/CU achievable -> regalloc
// occupancy target 5 waves/EU -> VGPR budget ~102 (no acc spill). A smaller
// LDS raises the target to 8 waves/EU -> 64-reg budget -> acc spill (R9).
#define LDSWORDS 5376               // 21504 B; payload = 2*BUFW = 2592 dw

#define AS1 __attribute__((address_space(1)))
#define AS3 __attribute__((address_space(3)))

__device__ __forceinline__ void gld16(const float* gp, float* lp) {
    // HBM/L2 -> LDS direct; LDS dest = wave-uniform base + lane*16
    __builtin_amdgcn_global_load_lds((const AS1 float*)gp,
                                     (AS3 float*)(unsigned long long)lp, 16, 0, 0);
}

__global__ __launch_bounds__(192, 4)
void corr_kernel(const float* __restrict__ f1g,
                 const float* __restrict__ f2g,
                 float* __restrict__ out)
{
    __shared__ float lds[LDSWORDS];

    const int tid  = threadIdx.x;
    const int wave = tid >> 6;          // dh-within-group AND staging channel idx
    const int lane = tid & 63;
    const int row  = lane >> 2;         // 0..15
    const int colb = (lane & 3) << 2;   // 0,4,8,12

    // XCD swizzle: 4800 = 8 XCDs x 600 (bijective). XCD owns batch b; the 3
    // dh-groups of a tile are dispatch-adjacent (halo/L2 reuse).
    const int bid  = blockIdx.x;
    const int ebid = (bid & 7) * 600 + (bid >> 3);
    const int b    = ebid / 600;
    const int t6   = ebid - b * 600;
    const int g    = t6 % 3;            // dh = 3g + wave
    const int tile = t6 / 3;
    const int by   = tile / 20, bx = tile - by * 20;
    const int x0 = bx * TW, y0 = by * TH;
    const int HWi  = H_ * W_;
    const int r0   = y0 + 3 * g - 4;    // first f2 halo row (global)

    const float* f1b = f1g + (size_t)b * C_ * HWi;
    const float* f2b = f2g + (size_t)b * C_ * HWi;

    // f1: direct global->reg, thread's own 4 px (L1-shared across the 3 waves)
    const float* f1p = f1b + (y0 + row) * W_ + x0 + colb;

    // f2 staging lane maps (2 gld16 parts per 432-dw channel-plane):
    // slot s -> dw 4s, r = s/6, c = 4*(s%6); part0 s=lane, part1 s=64+lane (s<108).
    // Halo x-offset (4) == segment width -> segment fully in or fully out:
    // predicate gx in [0, W-4] is exact.
    int so0, so1; bool p0, p1;
    {
        int s, r, c, gy, gx;
        s = lane;      r = s / 6; c = (s - 6 * r) << 2;
        gy = r0 + r;   gx = x0 - 4 + c;
        p0 = (gy >= 0) & (gy < H_) & (gx >= 0) & (gx <= W_ - 4);
        so0 = gy * W_ + gx;
        s = 64 + lane; r = s / 6; c = (s - 6 * r) << 2;
        gy = r0 + r;   gx = x0 - 4 + c;
        p1 = (s < 108) & (gy >= 0) & (gy < H_) & (gx >= 0) & (gx <= W_ - 4);
        so1 = gy * W_ + gx;
    }

    // compute-side read base: f2 lds row = out_row + wave
    const int o0 = (row + wave) * F2STRIDE + colb;

    // stage chunk cb..cb+2: wave w stages channel cb+w (2 predicated gld16)
    auto stage = [&](int cb, int bufb) {
        const int co = (cb + wave) * HWi;
        float* l = &lds[bufb + wave * F2PLANE];
        if (p0) gld16(f2b + co + so0, l);
        if (p1) gld16(f2b + co + so1, l + 256);
    };

    float4 acc0, acc1, acc2, acc3, acc4, acc5, acc6, acc7, acc8;
    acc0 = acc1 = acc2 = acc3 = acc4 = acc5 = acc6 = acc7 = acc8 = make_float4(0.f, 0.f, 0.f, 0.f);
    float4 P0, P1, P2;

#define F1LOAD(cb) {                                         \
        P0 = *(const float4*)(f1p + (cb) * HWi);             \
        P1 = *(const float4*)(f1p + ((cb) + 1) * HWi);       \
        P2 = *(const float4*)(f1p + ((cb) + 2) * HWi); }

#define STEPD(A, P, e0, e1, e2, e3)                          \
        A.x = fmaf(P.x, e0, A.x);                            \
        A.y = fmaf(P.y, e1, A.y);                            \
        A.z = fmaf(P.z, e2, A.z);                            \
        A.w = fmaf(P.w, e3, A.w);

#define COMPC(c, RB, P) {                                                         \
        const float4 q0 = *(const float4*)&lds[(RB) + c * F2PLANE + o0];          \
        const float4 q1 = *(const float4*)&lds[(RB) + c * F2PLANE + o0 + 4];      \
        const float4 q2 = *(const float4*)&lds[(RB) + c * F2PLANE + o0 + 8];      \
        STEPD(acc0, P, q0.x, q0.y, q0.z, q0.w)                                    \
        STEPD(acc1, P, q0.y, q0.z, q0.w, q1.x)                                    \
        STEPD(acc2, P, q0.z, q0.w, q1.x, q1.y)                                    \
        STEPD(acc3, P, q0.w, q1.x, q1.y, q1.z)                                    \
        STEPD(acc4, P, q1.x, q1.y, q1.z, q1.w)                                    \
        STEPD(acc5, P, q1.y, q1.z, q1.w, q2.x)                                    \
        STEPD(acc6, P, q1.z, q1.w, q2.x, q2.y)                                    \
        STEPD(acc7, P, q1.w, q2.x, q2.y, q2.z)                                    \
        STEPD(acc8, P, q2.x, q2.y, q2.z, q2.w)                                    \
    }

    // one-time zero (OOB slots are never DMA'd; payload rewritten every chunk)
    for (int t = tid; t < LDSWORDS; t += 192) lds[t] = 0.f;
    __syncthreads();
    stage(0, 0);                          // chunk 0 -> buf 0

#pragma unroll 1
    for (int kk = 0; kk < NCH / 2; ++kk) {
        const int c0 = 6 * kk;            // chunk 2kk channels c0..c0+2
        __syncthreads();                  // chunk-2kk DMA drained (vmcnt in barrier)
        F1LOAD(c0)                        // f1 loads BEFORE stage: no DMA drain on use
        stage(c0 + 3, BUFW);              // prefetch chunk 2kk+1 -> buf 1
        COMPC(0, 0, P0) COMPC(1, 0, P1) COMPC(2, 0, P2)
        __syncthreads();
        F1LOAD(c0 + 3)
        if (kk < NCH / 2 - 1) stage(c0 + 6, 0);
        COMPC(0, BUFW, P0) COMPC(1, BUFW, P1) COMPC(2, BUFW, P2)
    }

    // ---- epilogue: dh = 3g + wave; out[b, dh*9+d, y0+row, x0+colb..+3] ----
    const int dh = 3 * g + wave;
    const int gy = y0 + row;
    const int gx = x0 + colb;
#define STORED(d) {                                                                 \
        float* op_ = out + (size_t)((b * NDD + dh * ND + d) * H_ + gy) * W_ + gx;   \
        *(float4*)op_ = acc##d; }
    STORED(0) STORED(1) STORED(2) STORED(3) STORED(4)
    STORED(5) STORED(6) STORED(7) STORED(8)
}

extern "C" void kernel_launch(void* const* d_in, const int* in_sizes, int n_in,
                              void* d_out, int out_size, void* d_ws, size_t ws_size,
                              hipStream_t stream)
{
    const float* f1 = (const float*)d_in[0];
    const float* f2 = (const float*)d_in[1];
    float* out = (float*)d_out;
    corr_kernel<<<dim3(4800), 192, 0, stream>>>(f1, f2, out);
}